// Round 1
// baseline (8235.020 us; speedup 1.0000x reference)
//
#include <hip/hip_runtime.h>

// LSTM w/ hard-sigmoid gates. T=512, B=64, I=H=512.
// Persistent kernel: 4 replicas (16 batches each) x 16 WGs (512 thr = 8 waves).
// Each wave holds 16 gate rows x 1024 K of [w_ih|w_hh] as bf16 MFMA A-frags in
// 128 VGPRs for the whole kernel. Per-replica monotonic-counter barrier per step.
// Workspace: [0,1024)   : 4 arrival counters (256B stride)  -- memset to 0
//            [4096, +128K): h double buffer [2][64][512] bf16

#define T_LEN 512
#define BATCH 64
#define ISZ   512
#define HSZ   512

#define NREP       4
#define WG_PER_REP 16
#define BR         16   // batches per replica
#define JW         32   // h columns per WG
#define NWG   (NREP * WG_PER_REP)
#define NTHR  512

typedef __bf16 bf16x8 __attribute__((ext_vector_type(8)));
typedef float  f32x4  __attribute__((ext_vector_type(4)));
typedef float  f32x8  __attribute__((ext_vector_type(8)));

__device__ __forceinline__ bf16x8 cvt8(const float4 a, const float4 b) {
  f32x8 t;
  t[0] = a.x; t[1] = a.y; t[2] = a.z; t[3] = a.w;
  t[4] = b.x; t[5] = b.y; t[6] = b.z; t[7] = b.w;
  return __builtin_convertvector(t, bf16x8);   // v_cvt_pk_bf16_f32 pairs
}

__device__ __forceinline__ float fast_tanh(float v) {
  float e = __expf(2.0f * v);
  return 1.0f - 2.0f / (e + 1.0f);   // exact limits at +-inf
}

__device__ __forceinline__ float hsig(float v) {
  return fminf(fmaxf(0.2f * v + 0.5f, 0.0f), 1.0f);
}

__global__ __launch_bounds__(NTHR, 2) void lstm_kernel(
    const float* __restrict__ x,      // [T][B][I]
    const float* __restrict__ h0,     // [B][H]
    const float* __restrict__ c0,     // [B][H]
    const float* __restrict__ w_ih,   // [4H][I]
    const float* __restrict__ w_hh,   // [4H][H]
    const float* __restrict__ b_ih,   // [4H]
    const float* __restrict__ b_hh,   // [4H]
    float* __restrict__ out,          // [T][B][H] ++ hn[B][H] ++ cn[B][H]
    unsigned* __restrict__ cnt,       // per-replica counters, stride 64 u32
    __bf16* __restrict__ hbuf)        // [2][B][H]
{
  const int bid = blockIdx.x;
  // consecutive blocks round-robin XCDs: pack each replica onto ~2 XCDs
  const int rep = (bid >> 1) & 3;
  const int wgi = ((bid >> 3) << 1) | (bid & 1);
  const int B0  = rep * BR;
  const int J0  = wgi * JW;

  const int tid  = threadIdx.x;
  const int lane = tid & 63;
  const int wv   = tid >> 6;          // 0..7
  const int gt   = wv >> 1;           // gate type: 0=i 1=f 2=g 3=o
  const int jh   = wv & 1;            // which 16-col half of this WG's 32 cols

  const int l15 = lane & 15;
  const int lk  = (lane >> 4) << 3;   // k offset of this lane's 8-elem frag
  const int cd4 = (lane >> 4) << 2;   // C/D row group

  unsigned* myc = cnt + rep * 64;     // 256B apart

  // ---- weights -> registers (A-frags; row = lane&15, k-group = lane>>4) ----
  bf16x8 wfrag[32];
  {
    const int grow = gt * HSZ + J0 + jh * 16 + l15;
    const float* wi = w_ih + (size_t)grow * ISZ + lk;
    const float* wh = w_hh + (size_t)grow * HSZ + lk;
#pragma unroll
    for (int kc = 0; kc < 16; ++kc) {
      float4 a = *(const float4*)(wi + kc * 32);
      float4 b = *(const float4*)(wi + kc * 32 + 4);
      wfrag[kc] = cvt8(a, b);
    }
#pragma unroll
    for (int kc = 0; kc < 16; ++kc) {
      float4 a = *(const float4*)(wh + kc * 32);
      float4 b = *(const float4*)(wh + kc * 32 + 4);
      wfrag[16 + kc] = cvt8(a, b);
    }
  }

  // ---- bias in C/D layout (acc init each step) ----
  float bias[4];
#pragma unroll
  for (int r = 0; r < 4; ++r) {
    int g = gt * HSZ + J0 + jh * 16 + cd4 + r;
    bias[r] = b_ih[g] + b_hh[g];
  }

  // ---- cell state + h0 publish (update-phase distribution: 16b x 32j) ----
  const int ub = tid >> 5;            // local batch 0..15
  const int uj = tid & 31;            // local col   0..31
  const size_t urow = (size_t)(B0 + ub) * HSZ + (size_t)(J0 + uj);
  float cst = c0[urow];
  hbuf[urow] = (__bf16)h0[urow];      // buffer 0 holds h_0

  __syncthreads();                    // drains the hbuf stores (vmcnt before barrier)
  if (tid == 0) {
    __builtin_amdgcn_fence(__ATOMIC_RELEASE, "agent");
    __hip_atomic_fetch_add(myc, 1u, __ATOMIC_RELAXED, __HIP_MEMORY_SCOPE_AGENT);
  }

  __shared__ float lds_g[16][4][33];  // [b][gate][j], padded: 2-way max (free)

  for (int t = 0; t < T_LEN; ++t) {
    f32x4 acc;
    acc[0] = bias[0]; acc[1] = bias[1]; acc[2] = bias[2]; acc[3] = bias[3];

    // x contribution -- independent of the recurrence, issued before the wait
    const float* xr = x + ((size_t)t * BATCH + (size_t)(B0 + l15)) * ISZ + lk;
#pragma unroll
    for (int kc = 0; kc < 16; ++kc) {
      float4 a = *(const float4*)(xr + kc * 32);
      float4 b = *(const float4*)(xr + kc * 32 + 4);
      acc = __builtin_amdgcn_mfma_f32_16x16x32_bf16(wfrag[kc], cvt8(a, b), acc, 0, 0, 0);
    }

    // wait until all 16 WGs of this replica have published h_t
    if (tid == 0) {
      const unsigned target = (unsigned)WG_PER_REP * (unsigned)(t + 1);
      long guard = 0;
      while (__hip_atomic_load(myc, __ATOMIC_RELAXED, __HIP_MEMORY_SCOPE_AGENT) < target) {
        __builtin_amdgcn_s_sleep(2);
        if (++guard > (1L << 24)) break;   // safety net: corrupt, don't hang
      }
    }
    __syncthreads();
    __builtin_amdgcn_fence(__ATOMIC_ACQUIRE, "agent");  // invalidate stale L1/L2

    // h contribution (B-frags straight from the global double buffer)
    const __bf16* hr = hbuf + (size_t)(t & 1) * BATCH * HSZ
                            + (size_t)(B0 + l15) * HSZ + lk;
#pragma unroll
    for (int kc = 0; kc < 16; ++kc) {
      bf16x8 hb = *(const bf16x8*)(hr + kc * 32);
      acc = __builtin_amdgcn_mfma_f32_16x16x32_bf16(wfrag[16 + kc], hb, acc, 0, 0, 0);
    }

    // gates -> LDS (C/D: col=lane&15 -> batch, row=(lane>>4)*4+r -> j offset)
#pragma unroll
    for (int r = 0; r < 4; ++r) {
      lds_g[l15][gt][jh * 16 + cd4 + r] = acc[r];
    }
    __syncthreads();

    // cell update: one (b, j) pair per thread
    float gi = lds_g[ub][0][uj];
    float gf = lds_g[ub][1][uj];
    float gg = lds_g[ub][2][uj];
    float go = lds_g[ub][3][uj];
    float iv = hsig(gi), fv = hsig(gf), ov = hsig(go);
    float gv = fast_tanh(gg);
    cst = fv * cst + iv * gv;
    float hv = ov * fast_tanh(cst);

    out[(size_t)t * BATCH * HSZ + urow] = hv;
    hbuf[(size_t)((t + 1) & 1) * BATCH * HSZ + urow] = (__bf16)hv;
    if (t == T_LEN - 1) {
      out[(size_t)T_LEN * BATCH * HSZ + urow] = hv;                       // hn
      out[(size_t)T_LEN * BATCH * HSZ + (size_t)BATCH * HSZ + urow] = cst; // cn
    }

    __syncthreads();   // drains all waves' h/out stores + protects lds_g reuse
    if (tid == 0) {
      __builtin_amdgcn_fence(__ATOMIC_RELEASE, "agent");  // wbL2: publish h_{t+1}
      __hip_atomic_fetch_add(myc, 1u, __ATOMIC_RELAXED, __HIP_MEMORY_SCOPE_AGENT);
    }
  }
}

extern "C" void kernel_launch(void* const* d_in, const int* in_sizes, int n_in,
                              void* d_out, int out_size, void* d_ws, size_t ws_size,
                              hipStream_t stream) {
  const float* x    = (const float*)d_in[0];
  const float* h0   = (const float*)d_in[1];
  const float* c0   = (const float*)d_in[2];
  const float* w_ih = (const float*)d_in[3];
  const float* w_hh = (const float*)d_in[4];
  const float* b_ih = (const float*)d_in[5];
  const float* b_hh = (const float*)d_in[6];
  float* out = (float*)d_out;

  unsigned* cnt = (unsigned*)d_ws;
  __bf16* hbuf  = (__bf16*)((char*)d_ws + 4096);
  // needs 4096 + 2*64*512*2 = ~132KB of workspace

  hipMemsetAsync(d_ws, 0, 1024, stream);  // zero arrival counters (ws is poisoned)

  hipLaunchKernelGGL(lstm_kernel, dim3(NWG), dim3(NTHR), 0, stream,
                     x, h0, c0, w_ih, w_hh, b_ih, b_hh, out, cnt, hbuf);
}

// Round 2
// 5895.811 us; speedup vs baseline: 1.3968x; 1.3968x over previous
//
#include <hip/hip_runtime.h>

// LSTM w/ hard-sigmoid gates. T=512, B=64, I=H=512.
// Persistent kernel: 4 replicas (16 batches each) x 16 WGs (512 thr = 8 waves).
// Each wave holds 16 gate rows x 1024 K of [w_ih|w_hh] as bf16 MFMA A-frags in
// 128 VGPRs for the whole kernel.
//
// Round 2 change: NO agent fences (R1: per-step wbL2/invL2 = 16us/step).
// All cross-WG data (hbuf, counters) moves through sc0+sc1 accesses that
// bypass L1/L2 straight to the device-coherent memory-side L3. Ordering:
// __syncthreads' vmcnt(0) drain before the counter increment (producer),
// spin-load -> asm sc0sc1 loads -> s_waitcnt vmcnt(0) -> sched_barrier(0)
// (consumer).
//
// Workspace: [0,1024)    : 4 arrival counters (256B stride) -- memset to 0
//            [4096,+128K): h double buffer [2][64][512] bf16

#define T_LEN 512
#define BATCH 64
#define ISZ   512
#define HSZ   512

#define NREP       4
#define WG_PER_REP 16
#define BR         16   // batches per replica
#define JW         32   // h columns per WG
#define NWG   (NREP * WG_PER_REP)
#define NTHR  512

typedef __bf16 bf16x8 __attribute__((ext_vector_type(8)));
typedef float  f32x4  __attribute__((ext_vector_type(4)));
typedef float  f32x8  __attribute__((ext_vector_type(8)));
typedef int    i32x4  __attribute__((ext_vector_type(4)));

__device__ __forceinline__ bf16x8 cvt8(const float4 a, const float4 b) {
  f32x8 t;
  t[0] = a.x; t[1] = a.y; t[2] = a.z; t[3] = a.w;
  t[4] = b.x; t[5] = b.y; t[6] = b.z; t[7] = b.w;
  return __builtin_convertvector(t, bf16x8);
}

__device__ __forceinline__ float fast_tanh(float v) {
  float e = __expf(2.0f * v);
  return 1.0f - 2.0f / (e + 1.0f);   // exact limits at +-inf
}

__device__ __forceinline__ float hsig(float v) {
  return fminf(fmaxf(0.2f * v + 0.5f, 0.0f), 1.0f);
}

__device__ __forceinline__ unsigned pack_bf16(float a, float b) {
  union { __bf16 h[2]; unsigned u; } p;
  p.h[0] = (__bf16)a; p.h[1] = (__bf16)b;
  return p.u;
}

// sc0 sc1 = bypass L1+L2, served at the device-coherent point (L3/memory)
#define HLOAD(i, o)                                                        \
  asm volatile("global_load_dwordx4 %0, %1, off offset:" #o " sc0 sc1"     \
               : "=v"(hfrag[i]) : "v"(hr));

__global__ __launch_bounds__(NTHR, 2) void lstm_kernel(
    const float* __restrict__ x,      // [T][B][I]
    const float* __restrict__ h0,     // [B][H]
    const float* __restrict__ c0,     // [B][H]
    const float* __restrict__ w_ih,   // [4H][I]
    const float* __restrict__ w_hh,   // [4H][H]
    const float* __restrict__ b_ih,   // [4H]
    const float* __restrict__ b_hh,   // [4H]
    float* __restrict__ out,          // [T][B][H] ++ hn[B][H] ++ cn[B][H]
    unsigned* __restrict__ cnt,       // per-replica counters, stride 64 u32
    __bf16* __restrict__ hbuf)        // [2][B][H]
{
  const int bid = blockIdx.x;
  // bid%8 round-robins XCDs: replica r's 16 WGs sit on XCDs {2r, 2r+1}
  const int rep = (bid >> 1) & 3;
  const int wgi = ((bid >> 3) << 1) | (bid & 1);
  const int B0  = rep * BR;
  const int J0  = wgi * JW;

  const int tid  = threadIdx.x;
  const int lane = tid & 63;
  const int wv   = tid >> 6;          // 0..7
  const int gt   = wv >> 1;           // gate type: 0=i 1=f 2=g 3=o
  const int jh   = wv & 1;            // which 16-col half of this WG's 32 cols

  const int l15 = lane & 15;
  const int lk  = (lane >> 4) << 3;   // k offset of this lane's 8-elem frag
  const int cd4 = (lane >> 4) << 2;   // C/D row group

  unsigned* myc = cnt + rep * 64;     // 256B apart
  unsigned* hbuf32 = (unsigned*)hbuf;

  // ---- weights -> registers (A-frags; row = lane&15, k-group = lane>>4) ----
  bf16x8 wfrag[32];
  {
    const int grow = gt * HSZ + J0 + jh * 16 + l15;
    const float* wi = w_ih + (size_t)grow * ISZ + lk;
    const float* wh = w_hh + (size_t)grow * HSZ + lk;
#pragma unroll
    for (int kc = 0; kc < 16; ++kc) {
      float4 a = *(const float4*)(wi + kc * 32);
      float4 b = *(const float4*)(wi + kc * 32 + 4);
      wfrag[kc] = cvt8(a, b);
    }
#pragma unroll
    for (int kc = 0; kc < 16; ++kc) {
      float4 a = *(const float4*)(wh + kc * 32);
      float4 b = *(const float4*)(wh + kc * 32 + 4);
      wfrag[16 + kc] = cvt8(a, b);
    }
  }

  // ---- bias in C/D layout (acc init each step) ----
  float bias[4];
#pragma unroll
  for (int r = 0; r < 4; ++r) {
    int g = gt * HSZ + J0 + jh * 16 + cd4 + r;
    bias[r] = b_ih[g] + b_hh[g];
  }

  // ---- update-phase distribution: 256 active threads, (b, j-pair) each ----
  const int act = (tid < 256);
  const int ub  = (tid >> 4) & 15;    // local batch 0..15
  const int jp  = tid & 15;           // j-pair 0..15  -> j = 2jp, 2jp+1
  const size_t urow = (size_t)(B0 + ub) * HSZ + (size_t)(J0 + 2 * jp);

  float cst0 = 0.f, cst1 = 0.f;
  if (act) {
    float2 cc = *(const float2*)&c0[urow];
    cst0 = cc.x; cst1 = cc.y;
    float2 hh = *(const float2*)&h0[urow];
    __hip_atomic_store(&hbuf32[urow >> 1], pack_bf16(hh.x, hh.y),
                       __ATOMIC_RELAXED, __HIP_MEMORY_SCOPE_AGENT);
  }

  __syncthreads();                    // drains hbuf stores (vmcnt(0) per wave)
  if (tid == 0) {
    __hip_atomic_fetch_add(myc, 1u, __ATOMIC_RELAXED, __HIP_MEMORY_SCOPE_AGENT);
  }

  // gate exchange: [b][gate][j] pad 36 -> float4 writes conflict-free,
  // float2 reads 2-way (free)
  __shared__ __align__(16) float lds_g[16][4][36];

  for (int t = 0; t < T_LEN; ++t) {
    f32x4 acc;
    acc[0] = bias[0]; acc[1] = bias[1]; acc[2] = bias[2]; acc[3] = bias[3];

    // x contribution -- independent of the recurrence, issued before the wait
    const float* xr = x + ((size_t)t * BATCH + (size_t)(B0 + l15)) * ISZ + lk;
#pragma unroll
    for (int kc = 0; kc < 16; ++kc) {
      float4 a = *(const float4*)(xr + kc * 32);
      float4 b = *(const float4*)(xr + kc * 32 + 4);
      acc = __builtin_amdgcn_mfma_f32_16x16x32_bf16(wfrag[kc], cvt8(a, b), acc, 0, 0, 0);
    }

    // per-wave spin until all 16 WGs of this replica published h_t
    {
      const unsigned target = (unsigned)WG_PER_REP * (unsigned)(t + 1);
      if (lane == 0) {
        long guard = 0;
        while (__hip_atomic_load(myc, __ATOMIC_RELAXED, __HIP_MEMORY_SCOPE_AGENT) < target) {
          __builtin_amdgcn_s_sleep(1);
          if (++guard > (1L << 22)) break;   // safety net: corrupt, don't hang
        }
      }
      // wave reconverges here; no cache maintenance needed (loads below bypass)
    }
    __builtin_amdgcn_sched_barrier(0);

    // h contribution: B-frags from the global double buffer, L2-bypassing
    const __bf16* hr = hbuf + (size_t)(t & 1) * BATCH * HSZ
                            + (size_t)(B0 + l15) * HSZ + lk;
    i32x4 hfrag[16];
    HLOAD(0, 0)    HLOAD(1, 64)   HLOAD(2, 128)  HLOAD(3, 192)
    HLOAD(4, 256)  HLOAD(5, 320)  HLOAD(6, 384)  HLOAD(7, 448)
    HLOAD(8, 512)  HLOAD(9, 576)  HLOAD(10, 640) HLOAD(11, 704)
    HLOAD(12, 768) HLOAD(13, 832) HLOAD(14, 896) HLOAD(15, 960)
    asm volatile("s_waitcnt vmcnt(0)" ::: "memory");
    __builtin_amdgcn_sched_barrier(0);   // rule #18: keep MFMAs below the wait

#pragma unroll
    for (int kc = 0; kc < 16; ++kc) {
      bf16x8 hb = __builtin_bit_cast(bf16x8, hfrag[kc]);
      acc = __builtin_amdgcn_mfma_f32_16x16x32_bf16(wfrag[16 + kc], hb, acc, 0, 0, 0);
    }

    // gates -> LDS (C/D: col=lane&15 -> batch, row=(lane>>4)*4+r -> j offset)
    *(f32x4*)&lds_g[l15][gt][jh * 16 + cd4] = acc;
    __syncthreads();

    // cell update: one (b, j-pair) per thread, 256 threads
    if (act) {
      float2 gi = *(const float2*)&lds_g[ub][0][2 * jp];
      float2 gf = *(const float2*)&lds_g[ub][1][2 * jp];
      float2 gg = *(const float2*)&lds_g[ub][2][2 * jp];
      float2 go = *(const float2*)&lds_g[ub][3][2 * jp];

      float i0 = hsig(gi.x), f0 = hsig(gf.x), o0 = hsig(go.x);
      float i1 = hsig(gi.y), f1 = hsig(gf.y), o1 = hsig(go.y);
      float g0 = fast_tanh(gg.x), g1 = fast_tanh(gg.y);
      cst0 = f0 * cst0 + i0 * g0;
      cst1 = f1 * cst1 + i1 * g1;
      float hv0 = o0 * fast_tanh(cst0);
      float hv1 = o1 * fast_tanh(cst1);

      float2 hv; hv.x = hv0; hv.y = hv1;
      *(float2*)&out[(size_t)t * BATCH * HSZ + urow] = hv;

      __hip_atomic_store(&hbuf32[((size_t)((t + 1) & 1) * BATCH * HSZ + urow) >> 1],
                         pack_bf16(hv0, hv1),
                         __ATOMIC_RELAXED, __HIP_MEMORY_SCOPE_AGENT);

      if (t == T_LEN - 1) {
        *(float2*)&out[(size_t)T_LEN * BATCH * HSZ + urow] = hv;           // hn
        float2 cv; cv.x = cst0; cv.y = cst1;
        *(float2*)&out[(size_t)T_LEN * BATCH * HSZ + (size_t)BATCH * HSZ + urow] = cv; // cn
      }
    }

    __syncthreads();   // drains ALL waves' sc0sc1 h-stores + protects lds_g
    if (tid == 0) {
      __hip_atomic_fetch_add(myc, 1u, __ATOMIC_RELAXED, __HIP_MEMORY_SCOPE_AGENT);
    }
  }
}

extern "C" void kernel_launch(void* const* d_in, const int* in_sizes, int n_in,
                              void* d_out, int out_size, void* d_ws, size_t ws_size,
                              hipStream_t stream) {
  const float* x    = (const float*)d_in[0];
  const float* h0   = (const float*)d_in[1];
  const float* c0   = (const float*)d_in[2];
  const float* w_ih = (const float*)d_in[3];
  const float* w_hh = (const float*)d_in[4];
  const float* b_ih = (const float*)d_in[5];
  const float* b_hh = (const float*)d_in[6];
  float* out = (float*)d_out;

  unsigned* cnt = (unsigned*)d_ws;
  __bf16* hbuf  = (__bf16*)((char*)d_ws + 4096);
  // needs 4096 + 2*64*512*2 = ~132KB of workspace

  hipMemsetAsync(d_ws, 0, 1024, stream);  // zero arrival counters (ws is poisoned)

  hipLaunchKernelGGL(lstm_kernel, dim3(NWG), dim3(NTHR), 0, stream,
                     x, h0, c0, w_ih, w_hh, b_ih, b_hh, out, cnt, hbuf);
}